// Round 2
// baseline (22482.451 us; speedup 1.0000x reference)
//
#include <hip/hip_runtime.h>
#include <hip/hip_bf16.h>
#include <math.h>

// Problem constants
static constexpr int BATCH = 16;
static constexpr int SEQ   = 197;   // NP*NP + 1
static constexpr int DMODEL= 768;
static constexpr int NHEAD = 12;
static constexpr int DHEAD = 64;
static constexpr int NMLP  = 3072;
static constexpr int NLAYER= 12;
static constexpr int NCLS  = 1000;
static constexpr int NPATCHES = 196;

// ---------------------------------------------------------------------------
// Generic GEMM: C[M,N] = op( A[M,K] @ B[N,K]^T + bias[n] )   (all fp32)
// mode 0: C = acc + bias
// mode 1: C = gelu(acc + bias)          (exact gelu, erf)
// mode 2: C += acc + bias               (residual accumulate, C preloaded)
// ---------------------------------------------------------------------------
static constexpr int BM = 64, BN = 64, BK = 16;

__global__ __launch_bounds__(256) void gemm_kernel(
    const float* __restrict__ A, const float* __restrict__ Bw,
    const float* __restrict__ bias, float* __restrict__ C,
    int M, int N, int K, int mode)
{
    __shared__ float As[BK][BM];
    __shared__ float Bs[BK][BN];
    const int bm = blockIdx.y * BM;
    const int bn = blockIdx.x * BN;
    const int t  = threadIdx.x;
    const int tx = t & 15, ty = t >> 4;
    const int row = t >> 2;        // 0..63
    const int kq  = (t & 3) * 4;   // 0,4,8,12

    float acc[4][4] = {};

    for (int k0 = 0; k0 < K; k0 += BK) {
        const int gm = bm + row;
        const int gn = bn + row;
        #pragma unroll
        for (int i = 0; i < 4; ++i) {
            int gk = k0 + kq + i;
            As[kq + i][row] = (gm < M && gk < K) ? A[(size_t)gm * K + gk] : 0.0f;
            Bs[kq + i][row] = (gn < N && gk < K) ? Bw[(size_t)gn * K + gk] : 0.0f;
        }
        __syncthreads();
        #pragma unroll
        for (int kk = 0; kk < BK; ++kk) {
            float a[4], b[4];
            #pragma unroll
            for (int i = 0; i < 4; ++i) a[i] = As[kk][ty * 4 + i];
            #pragma unroll
            for (int j = 0; j < 4; ++j) b[j] = Bs[kk][tx * 4 + j];
            #pragma unroll
            for (int i = 0; i < 4; ++i)
                #pragma unroll
                for (int j = 0; j < 4; ++j)
                    acc[i][j] = fmaf(a[i], b[j], acc[i][j]);
        }
        __syncthreads();
    }

    #pragma unroll
    for (int i = 0; i < 4; ++i) {
        int m = bm + ty * 4 + i;
        if (m >= M) continue;
        #pragma unroll
        for (int j = 0; j < 4; ++j) {
            int n = bn + tx * 4 + j;
            if (n >= N) continue;
            float v = acc[i][j] + (bias ? bias[n] : 0.0f);
            if (mode == 1) v = 0.5f * v * (1.0f + erff(v * 0.70710678118654752f));
            size_t idx = (size_t)m * N + n;
            if (mode == 2) C[idx] += v; else C[idx] = v;
        }
    }
}

// ---------------------------------------------------------------------------
// Patchify: images (B,3,224,224) fp32 -> patches (B,196,768) fp32
// p = py*14+px ; k = c*256 + iy*16 + ix
// ---------------------------------------------------------------------------
__global__ void patchify_kernel(const float* __restrict__ images,
                                float* __restrict__ patches, int total)
{
    int idx = blockIdx.x * 256 + threadIdx.x;
    if (idx >= total) return;
    int kidx = idx % 768;
    int p = (idx / 768) % NPATCHES;
    int b = idx / (768 * NPATCHES);
    int c  = kidx >> 8;
    int rem = kidx & 255;
    int iy = rem >> 4, ix = rem & 15;
    int py = p / 14, px = p % 14;
    size_t src = (((size_t)(b * 3 + c) * 224) + py * 16 + iy) * 224 + px * 16 + ix;
    patches[idx] = images[src];
}

// ---------------------------------------------------------------------------
// Assemble residual stream: out(b,s,d) = (s==0 ? cls[d] : tokens[b,s-1,d]) + pe[s,d]
// ---------------------------------------------------------------------------
__global__ void assemble_kernel(const float* __restrict__ tokens,
                                const float* __restrict__ cls,
                                const float* __restrict__ pe,
                                float* __restrict__ out, int total)
{
    int idx = blockIdx.x * 256 + threadIdx.x;
    if (idx >= total) return;
    int d = idx % 768;
    int s = (idx / 768) % SEQ;
    int b = idx / (768 * SEQ);
    float v = (s == 0) ? cls[d]
                       : tokens[((size_t)b * NPATCHES + (s - 1)) * 768 + d];
    out[idx] = v + pe[(size_t)s * 768 + d];
}

// ---------------------------------------------------------------------------
// LayerNorm over last dim (768), block per row, fp32 in -> fp32 out
// ---------------------------------------------------------------------------
__global__ __launch_bounds__(256) void ln_kernel(const float* __restrict__ inp,
                                                 const float* __restrict__ g,
                                                 const float* __restrict__ beta,
                                                 float* __restrict__ xout)
{
    int r = blockIdx.x;
    const float* rowp = inp + (size_t)r * 768;
    float vals[3];
    float s = 0.f, s2 = 0.f;
    #pragma unroll
    for (int i = 0; i < 3; ++i) {
        float v = rowp[threadIdx.x + 256 * i];
        vals[i] = v; s += v; s2 += v * v;
    }
    __shared__ float rs[256], rs2[256];
    rs[threadIdx.x] = s; rs2[threadIdx.x] = s2;
    __syncthreads();
    for (int st = 128; st; st >>= 1) {
        if (threadIdx.x < st) {
            rs[threadIdx.x]  += rs[threadIdx.x + st];
            rs2[threadIdx.x] += rs2[threadIdx.x + st];
        }
        __syncthreads();
    }
    float mean = rs[0] * (1.0f / 768.0f);
    float var  = rs2[0] * (1.0f / 768.0f) - mean * mean;
    float rstd = rsqrtf(var + 1e-5f);
    #pragma unroll
    for (int i = 0; i < 3; ++i) {
        int d = threadIdx.x + 256 * i;
        xout[(size_t)r * 768 + d] =
            (vals[i] - mean) * rstd * g[d] + beta[d];
    }
}

// ---------------------------------------------------------------------------
// Attention: one wave (64 threads) per (b, h, s). q,k,v fp32 laid out as
// (b, s, h*64+e). Adds softmax(qk^T)*v directly into residual stream `out`
// (each block owns a disjoint 64-float slice).
// ---------------------------------------------------------------------------
__global__ __launch_bounds__(64) void attn_kernel(const float* __restrict__ q,
                                                  const float* __restrict__ k,
                                                  const float* __restrict__ v,
                                                  float* __restrict__ out)
{
    const int s = blockIdx.x;
    const int bh = blockIdx.y;
    const int b = bh / NHEAD, h = bh % NHEAD;
    const int lane = threadIdx.x;
    const float scale = 0.125f; // 1/sqrt(64)

    __shared__ float qs[64];
    __shared__ float ps[208];

    const size_t base = (size_t)b * SEQ * 768 + h * 64;
    qs[lane] = q[base + (size_t)s * 768 + lane];
    __syncthreads();

    float sc[4];
    float pmax = -3.4e38f;
    #pragma unroll
    for (int i = 0; i < 4; ++i) {
        int t = lane + 64 * i;
        float d = -3.4e38f;
        if (t < SEQ) {
            const float* krow = k + base + (size_t)t * 768;
            float acc = 0.f;
            for (int e = 0; e < 64; ++e) acc += qs[e] * krow[e];
            d = acc * scale;
        }
        sc[i] = d;
        pmax = fmaxf(pmax, d);
    }
    for (int off = 32; off; off >>= 1) pmax = fmaxf(pmax, __shfl_down(pmax, off));
    pmax = __shfl(pmax, 0);

    float psum = 0.f;
    #pragma unroll
    for (int i = 0; i < 4; ++i) {
        int t = lane + 64 * i;
        if (t < SEQ) {
            float e = expf(sc[i] - pmax);
            ps[t] = e;
            psum += e;
        }
    }
    for (int off = 32; off; off >>= 1) psum += __shfl_down(psum, off);
    psum = __shfl(psum, 0);
    float inv = 1.0f / psum;
    __syncthreads();

    // o[e=lane] = sum_t ps[t] * v[t][e]
    float o = 0.f;
    for (int t = 0; t < SEQ; ++t) o += ps[t] * v[base + (size_t)t * 768 + lane];
    out[((size_t)b * SEQ + s) * 768 + h * 64 + lane] += o * inv;
}

// ---------------------------------------------------------------------------
// Classifier: logits = out[:,0] @ Wc^T + bc ; softmax ; write fp32
// ---------------------------------------------------------------------------
__global__ __launch_bounds__(256) void cls_kernel(const float* __restrict__ out,
                                                  const float* __restrict__ Wc,
                                                  const float* __restrict__ bc,
                                                  float* __restrict__ dout)
{
    int b = blockIdx.x;
    __shared__ float pooled[768];
    __shared__ float logits[NCLS];
    __shared__ float red[256];

    for (int d = threadIdx.x; d < 768; d += 256)
        pooled[d] = out[(size_t)b * SEQ * 768 + d];
    __syncthreads();

    for (int j = threadIdx.x; j < NCLS; j += 256) {
        const float* wr = Wc + (size_t)j * 768;
        float acc = 0.f;
        for (int d = 0; d < 768; ++d) acc += pooled[d] * wr[d];
        logits[j] = acc + bc[j];
    }
    __syncthreads();

    float m = -3.4e38f;
    for (int j = threadIdx.x; j < NCLS; j += 256) m = fmaxf(m, logits[j]);
    red[threadIdx.x] = m; __syncthreads();
    for (int st = 128; st; st >>= 1) {
        if (threadIdx.x < st) red[threadIdx.x] = fmaxf(red[threadIdx.x], red[threadIdx.x + st]);
        __syncthreads();
    }
    m = red[0]; __syncthreads();

    float ssum = 0.f;
    for (int j = threadIdx.x; j < NCLS; j += 256) {
        float e = expf(logits[j] - m);
        logits[j] = e; ssum += e;
    }
    red[threadIdx.x] = ssum; __syncthreads();
    for (int st = 128; st; st >>= 1) {
        if (threadIdx.x < st) red[threadIdx.x] += red[threadIdx.x + st];
        __syncthreads();
    }
    float inv = 1.0f / red[0];
    __syncthreads();

    for (int j = threadIdx.x; j < NCLS; j += 256)
        dout[(size_t)b * NCLS + j] = logits[j] * inv;
}

// ---------------------------------------------------------------------------
extern "C" void kernel_launch(void* const* d_in, const int* in_sizes, int n_in,
                              void* d_out, int out_size, void* d_ws, size_t ws_size,
                              hipStream_t stream)
{
    const float* images  = (const float*)d_in[0];
    const float* Wm      = (const float*)d_in[1];
    const float* bm      = (const float*)d_in[2];
    const float* cls_tok = (const float*)d_in[3];
    const float* pe      = (const float*)d_in[4];
    const float* g1      = (const float*)d_in[5];
    const float* beta1   = (const float*)d_in[6];
    const float* Wq      = (const float*)d_in[7];
    const float* bq      = (const float*)d_in[8];
    const float* Wk      = (const float*)d_in[9];
    const float* bk      = (const float*)d_in[10];
    const float* Wv      = (const float*)d_in[11];
    const float* bv      = (const float*)d_in[12];
    const float* g2      = (const float*)d_in[13];
    const float* beta2   = (const float*)d_in[14];
    const float* W1      = (const float*)d_in[15];
    const float* b1      = (const float*)d_in[16];
    const float* W2      = (const float*)d_in[17];
    const float* b2      = (const float*)d_in[18];
    const float* Wc      = (const float*)d_in[19];
    const float* bc      = (const float*)d_in[20];
    float* outp = (float*)d_out;

    const size_t BS = (size_t)BATCH * SEQ; // 3152
    char* ws = (char*)d_ws;
    float* out = (float*)ws; ws += BS * 768 * sizeof(float);
    float* x   = (float*)ws; ws += BS * 768 * sizeof(float);
    float* q   = (float*)ws; ws += BS * 768 * sizeof(float);
    float* k   = (float*)ws; ws += BS * 768 * sizeof(float);
    float* v   = (float*)ws; ws += BS * 768 * sizeof(float);
    float* h   = (float*)ws; ws += BS * NMLP * sizeof(float);
    // patch-embed scratch overlaps the (not-yet-used) MLP buffer
    float* patches = h;
    float* tokens  = h + (size_t)BATCH * NPATCHES * 768;

    // 1) patch embedding
    int tot_p = BATCH * NPATCHES * 768;
    patchify_kernel<<<(tot_p + 255) / 256, 256, 0, stream>>>(images, patches, tot_p);
    gemm_kernel<<<dim3(768 / BN, (BATCH * NPATCHES + BM - 1) / BM), 256, 0, stream>>>(
        patches, Wm, bm, tokens, BATCH * NPATCHES, 768, 768, 0);
    int tot_a = (int)(BS * 768);
    assemble_kernel<<<(tot_a + 255) / 256, 256, 0, stream>>>(tokens, cls_tok, pe, out, tot_a);

    dim3 g768 (768 / BN,  (int)((BS + BM - 1) / BM));
    dim3 g3072(NMLP / BN, (int)((BS + BM - 1) / BM));

    for (int l = 0; l < NLAYER; ++l) {
        ln_kernel<<<(int)BS, 256, 0, stream>>>(out, g1 + l * 768, beta1 + l * 768, x);
        gemm_kernel<<<g768, 256, 0, stream>>>(x, Wq + (size_t)l * 768 * 768, bq + l * 768, q, (int)BS, 768, 768, 0);
        gemm_kernel<<<g768, 256, 0, stream>>>(x, Wk + (size_t)l * 768 * 768, bk + l * 768, k, (int)BS, 768, 768, 0);
        gemm_kernel<<<g768, 256, 0, stream>>>(x, Wv + (size_t)l * 768 * 768, bv + l * 768, v, (int)BS, 768, 768, 0);
        attn_kernel<<<dim3(SEQ, BATCH * NHEAD), 64, 0, stream>>>(q, k, v, out);
        ln_kernel<<<(int)BS, 256, 0, stream>>>(out, g2 + l * 768, beta2 + l * 768, x);
        gemm_kernel<<<g3072, 256, 0, stream>>>(x, W1 + (size_t)l * NMLP * 768, b1 + l * NMLP, h, (int)BS, NMLP, 768, 1);
        gemm_kernel<<<g768, 256, 0, stream>>>(h, W2 + (size_t)l * 768 * NMLP, b2 + l * 768, out, (int)BS, 768, NMLP, 2);
    }

    cls_kernel<<<BATCH, 256, 0, stream>>>(out, Wc, bc, outp);
}

// Round 3
// 6711.517 us; speedup vs baseline: 3.3498x; 3.3498x over previous
//
#include <hip/hip_runtime.h>
#include <hip/hip_bf16.h>
#include <math.h>

typedef __hip_bfloat16 bf16;
typedef unsigned short ushort_t;
typedef short bf16x8 __attribute__((ext_vector_type(8)));
typedef float f32x4 __attribute__((ext_vector_type(4)));

// Problem constants
static constexpr int BATCH = 16;
static constexpr int SEQ   = 197;   // NP*NP + 1
static constexpr int NHEAD = 12;
static constexpr int NMLP  = 3072;
static constexpr int NLAYER= 12;
static constexpr int NCLS  = 1000;
static constexpr int NPATCHES = 196;
static constexpr int MPAD  = 3200;  // padded row count for activation buffers

// ---------------------------------------------------------------------------
// async global->LDS, 16B per lane
// ---------------------------------------------------------------------------
__device__ __forceinline__ void load_lds16(const void* g, void* l) {
    __builtin_amdgcn_global_load_lds(
        (const __attribute__((address_space(1))) void*)g,
        (__attribute__((address_space(3))) void*)l, 16, 0, 0);
}

// ---------------------------------------------------------------------------
// MFMA GEMM: C[M,N] = op(A[M,K]bf16 @ B[N,K]^T bf16 + bias)
//   mode 0: Cf = v (fp32)
//   mode 1: Cb = bf16(gelu(v))
//   mode 2: Cf += v (fp32 residual accumulate)
// 128x128 tile, BK=32, 4 waves (2x2), 4x4 16x16x32 MFMAs per wave.
// LDS 16B-slots XOR-swizzled: slot(row,p) = row*4 + (p ^ ((row>>1)&3))
// N, K must be multiples of 128/32; M guarded on store (A buffer must have
// rows up to ceil(M/128)*128 allocated).
// ---------------------------------------------------------------------------
__global__ __launch_bounds__(256) void mfma_gemm(
    const ushort_t* __restrict__ A, const ushort_t* __restrict__ B,
    const float* __restrict__ bias, float* __restrict__ Cf,
    bf16* __restrict__ Cb, int M, int N, int K, int mode)
{
    __shared__ ushort_t As[128 * 32];
    __shared__ ushort_t Bs[128 * 32];

    const int t  = threadIdx.x;
    const int m0 = blockIdx.y * 128;
    const int n0 = blockIdx.x * 128;

    // staging: thread t owns LDS 16B-slot t (rows 0..63) and t+256 (rows 64..127)
    const int srow = t >> 2;                       // 0..63
    const int sp   = (t & 3) ^ ((srow >> 1) & 3);  // swizzled k-part to FETCH
    const int skp  = sp * 8;                       // shorts

    const int wave = t >> 6;
    const int lane = t & 63;
    const int wm   = (wave >> 1) * 64;
    const int wn   = (wave & 1) * 64;
    const int quad = lane >> 4;
    const int l16  = lane & 15;

    f32x4 acc[4][4] = {};

    const ushort_t* gA0 = A + (size_t)(m0 + srow) * K + skp;
    const ushort_t* gA1 = A + (size_t)(m0 + 64 + srow) * K + ((t & 3) ^ (((srow + 64) >> 1) & 3)) * 8;
    const ushort_t* gB0 = B + (size_t)(n0 + srow) * K + skp;
    const ushort_t* gB1 = B + (size_t)(n0 + 64 + srow) * K + ((t & 3) ^ (((srow + 64) >> 1) & 3)) * 8;
    ushort_t* lA0 = &As[t * 8];
    ushort_t* lA1 = &As[(t + 256) * 8];
    ushort_t* lB0 = &Bs[t * 8];
    ushort_t* lB1 = &Bs[(t + 256) * 8];

    for (int k0 = 0; k0 < K; k0 += 32) {
        load_lds16(gA0 + k0, lA0);
        load_lds16(gA1 + k0, lA1);
        load_lds16(gB0 + k0, lB0);
        load_lds16(gB1 + k0, lB1);
        __syncthreads();

        bf16x8 af[4], bfr[4];
        #pragma unroll
        for (int i = 0; i < 4; ++i) {
            int row = wm + i * 16 + l16;
            int s = quad ^ ((row >> 1) & 3);
            af[i] = *(const bf16x8*)&As[row * 32 + s * 8];
        }
        #pragma unroll
        for (int j = 0; j < 4; ++j) {
            int row = wn + j * 16 + l16;
            int s = quad ^ ((row >> 1) & 3);
            bfr[j] = *(const bf16x8*)&Bs[row * 32 + s * 8];
        }
        #pragma unroll
        for (int i = 0; i < 4; ++i)
            #pragma unroll
            for (int j = 0; j < 4; ++j)
                acc[i][j] = __builtin_amdgcn_mfma_f32_16x16x32_bf16(
                    af[i], bfr[j], acc[i][j], 0, 0, 0);
        __syncthreads();
    }

    // epilogue: C/D layout col=lane&15, row=(lane>>4)*4+reg
    #pragma unroll
    for (int i = 0; i < 4; ++i) {
        int mrow = m0 + wm + i * 16 + quad * 4;
        #pragma unroll
        for (int j = 0; j < 4; ++j) {
            int col = n0 + wn + j * 16 + l16;
            float bv = bias ? bias[col] : 0.0f;
            #pragma unroll
            for (int r = 0; r < 4; ++r) {
                int m = mrow + r;
                if (m >= M) continue;
                float v = acc[i][j][r] + bv;
                size_t idx = (size_t)m * N + col;
                if (mode == 1) {
                    v = 0.5f * v * (1.0f + erff(v * 0.70710678118654752f));
                    Cb[idx] = __float2bfloat16(v);
                } else if (mode == 2) {
                    Cf[idx] += v;
                } else {
                    Cf[idx] = v;
                }
            }
        }
    }
}

// ---------------------------------------------------------------------------
// fp32 -> bf16 elementwise (grid-stride, 4 per thread)
// ---------------------------------------------------------------------------
__global__ void f2b_kernel(const float* __restrict__ src, bf16* __restrict__ dst, int n)
{
    int i4 = (blockIdx.x * 256 + threadIdx.x) * 4;
    for (; i4 < n; i4 += gridDim.x * 1024) {
        float4 v = *(const float4*)(src + i4);
        dst[i4 + 0] = __float2bfloat16(v.x);
        dst[i4 + 1] = __float2bfloat16(v.y);
        dst[i4 + 2] = __float2bfloat16(v.z);
        dst[i4 + 3] = __float2bfloat16(v.w);
    }
}

// ---------------------------------------------------------------------------
// Per-layer weight conversion: Wq|Wk|Wv -> wqkv (bf16 [2304,768]),
// W1 -> w1b, W2 -> w2b, and bqkv fp32 concat [2304].
// ---------------------------------------------------------------------------
static constexpr int QKV_ELEMS = 3 * 768 * 768;     // 1769472
static constexpr int W1_ELEMS  = 3072 * 768;        // 2359296
static constexpr int CONV_VECS = (QKV_ELEMS + 2 * W1_ELEMS) / 4;  // 1622016
static constexpr int BIAS_VECS = 2304 / 4;          // 576

__global__ void convert_layer_kernel(
    const float* __restrict__ Wq, const float* __restrict__ Wk,
    const float* __restrict__ Wv, const float* __restrict__ W1,
    const float* __restrict__ W2, const float* __restrict__ bq,
    const float* __restrict__ bk, const float* __restrict__ bv,
    bf16* __restrict__ wqkv, bf16* __restrict__ w1b, bf16* __restrict__ w2b,
    float* __restrict__ bqkv)
{
    int idx = blockIdx.x * 256 + threadIdx.x;
    if (idx < BIAS_VECS) {
        int j = idx * 4;
        #pragma unroll
        for (int i = 0; i < 4; ++i) {
            int jj = j + i;
            float v = (jj < 768) ? bq[jj] : (jj < 1536) ? bk[jj - 768] : bv[jj - 1536];
            bqkv[jj] = v;
        }
    }
    int w = idx - BIAS_VECS;
    if (w < 0 || w >= CONV_VECS) return;
    const float* src;
    bf16* dst;
    int e;
    if (w < QKV_ELEMS / 4) {
        e = w * 4;
        int tsel = e / (768 * 768);
        int off = e - tsel * 768 * 768;
        src = (tsel == 0 ? Wq : tsel == 1 ? Wk : Wv) + off;
        dst = wqkv + tsel * 768 * 768 + off;
    } else if (w < QKV_ELEMS / 4 + W1_ELEMS / 4) {
        e = (w - QKV_ELEMS / 4) * 4;
        src = W1 + e;
        dst = w1b + e;
    } else {
        e = (w - QKV_ELEMS / 4 - W1_ELEMS / 4) * 4;
        src = W2 + e;
        dst = w2b + e;
    }
    float4 v = *(const float4*)src;
    dst[0] = __float2bfloat16(v.x);
    dst[1] = __float2bfloat16(v.y);
    dst[2] = __float2bfloat16(v.z);
    dst[3] = __float2bfloat16(v.w);
}

// ---------------------------------------------------------------------------
// Patchify: images (B,3,224,224) fp32 -> patches (B,196,768) bf16
// ---------------------------------------------------------------------------
__global__ void patchify_kernel(const float* __restrict__ images,
                                bf16* __restrict__ patches, int total)
{
    int idx = blockIdx.x * 256 + threadIdx.x;
    if (idx >= total) return;
    int kidx = idx % 768;
    int p = (idx / 768) % NPATCHES;
    int b = idx / (768 * NPATCHES);
    int c  = kidx >> 8;
    int rem = kidx & 255;
    int iy = rem >> 4, ix = rem & 15;
    int py = p / 14, px = p % 14;
    size_t src = (((size_t)(b * 3 + c) * 224) + py * 16 + iy) * 224 + px * 16 + ix;
    patches[idx] = __float2bfloat16(images[src]);
}

// ---------------------------------------------------------------------------
// Assemble residual stream (fp32)
// ---------------------------------------------------------------------------
__global__ void assemble_kernel(const float* __restrict__ tokens,
                                const float* __restrict__ cls,
                                const float* __restrict__ pe,
                                float* __restrict__ out, int total)
{
    int idx = blockIdx.x * 256 + threadIdx.x;
    if (idx >= total) return;
    int d = idx % 768;
    int s = (idx / 768) % SEQ;
    int b = idx / (768 * SEQ);
    float v = (s == 0) ? cls[d]
                       : tokens[((size_t)b * NPATCHES + (s - 1)) * 768 + d];
    out[idx] = v + pe[(size_t)s * 768 + d];
}

// ---------------------------------------------------------------------------
// LayerNorm (768), fp32 in -> bf16 out
// ---------------------------------------------------------------------------
__global__ __launch_bounds__(256) void ln_kernel(const float* __restrict__ inp,
                                                 const float* __restrict__ g,
                                                 const float* __restrict__ beta,
                                                 bf16* __restrict__ xout)
{
    int r = blockIdx.x;
    const float* rowp = inp + (size_t)r * 768;
    float vals[3];
    float s = 0.f, s2 = 0.f;
    #pragma unroll
    for (int i = 0; i < 3; ++i) {
        float v = rowp[threadIdx.x + 256 * i];
        vals[i] = v; s += v; s2 += v * v;
    }
    __shared__ float rs[256], rs2[256];
    rs[threadIdx.x] = s; rs2[threadIdx.x] = s2;
    __syncthreads();
    for (int st = 128; st; st >>= 1) {
        if (threadIdx.x < st) {
            rs[threadIdx.x]  += rs[threadIdx.x + st];
            rs2[threadIdx.x] += rs2[threadIdx.x + st];
        }
        __syncthreads();
    }
    float mean = rs[0] * (1.0f / 768.0f);
    float var  = rs2[0] * (1.0f / 768.0f) - mean * mean;
    float rstd = rsqrtf(var + 1e-5f);
    #pragma unroll
    for (int i = 0; i < 3; ++i) {
        int d = threadIdx.x + 256 * i;
        xout[(size_t)r * 768 + d] =
            __float2bfloat16((vals[i] - mean) * rstd * g[d] + beta[d]);
    }
}

// ---------------------------------------------------------------------------
// Attention on fused qkv buffer [M, 2304]: cols 0-767 q, 768-1535 k, 1536-2303 v.
// One wave per (b,h,s); adds softmax(qk^T)v into residual `out` (stride 768).
// ---------------------------------------------------------------------------
__global__ __launch_bounds__(64) void attn_kernel(const float* __restrict__ qkv,
                                                  float* __restrict__ out)
{
    const int s = blockIdx.x;
    const int bh = blockIdx.y;
    const int b = bh / NHEAD, h = bh % NHEAD;
    const int lane = threadIdx.x;
    const float scale = 0.125f; // 1/sqrt(64)

    __shared__ float qs[64];
    __shared__ float ps[208];

    const size_t rowbase = (size_t)b * SEQ;
    qs[lane] = qkv[(rowbase + s) * 2304 + h * 64 + lane];
    __syncthreads();

    float sc[4];
    float pmax = -3.4e38f;
    #pragma unroll
    for (int i = 0; i < 4; ++i) {
        int t = lane + 64 * i;
        float d = -3.4e38f;
        if (t < SEQ) {
            const float* krow = qkv + (rowbase + t) * 2304 + 768 + h * 64;
            float acc = 0.f;
            for (int e = 0; e < 64; ++e) acc += qs[e] * krow[e];
            d = acc * scale;
        }
        sc[i] = d;
        pmax = fmaxf(pmax, d);
    }
    for (int off = 32; off; off >>= 1) pmax = fmaxf(pmax, __shfl_down(pmax, off));
    pmax = __shfl(pmax, 0);

    float psum = 0.f;
    #pragma unroll
    for (int i = 0; i < 4; ++i) {
        int t = lane + 64 * i;
        if (t < SEQ) {
            float e = expf(sc[i] - pmax);
            ps[t] = e;
            psum += e;
        }
    }
    for (int off = 32; off; off >>= 1) psum += __shfl_down(psum, off);
    psum = __shfl(psum, 0);
    float inv = 1.0f / psum;
    __syncthreads();

    float o = 0.f;
    for (int t = 0; t < SEQ; ++t)
        o += ps[t] * qkv[(rowbase + t) * 2304 + 1536 + h * 64 + lane];
    out[((size_t)b * SEQ + s) * 768 + h * 64 + lane] += o * inv;
}

// ---------------------------------------------------------------------------
// Classifier (fp32 weights): logits = out[:,0] @ Wc^T + bc ; softmax
// ---------------------------------------------------------------------------
__global__ __launch_bounds__(256) void cls_kernel(const float* __restrict__ out,
                                                  const float* __restrict__ Wc,
                                                  const float* __restrict__ bc,
                                                  float* __restrict__ dout)
{
    int b = blockIdx.x;
    __shared__ float pooled[768];
    __shared__ float logits[NCLS];
    __shared__ float red[256];

    for (int d = threadIdx.x; d < 768; d += 256)
        pooled[d] = out[(size_t)b * SEQ * 768 + d];
    __syncthreads();

    for (int j = threadIdx.x; j < NCLS; j += 256) {
        const float* wr = Wc + (size_t)j * 768;
        float acc = 0.f;
        for (int d = 0; d < 768; ++d) acc += pooled[d] * wr[d];
        logits[j] = acc + bc[j];
    }
    __syncthreads();

    float m = -3.4e38f;
    for (int j = threadIdx.x; j < NCLS; j += 256) m = fmaxf(m, logits[j]);
    red[threadIdx.x] = m; __syncthreads();
    for (int st = 128; st; st >>= 1) {
        if (threadIdx.x < st) red[threadIdx.x] = fmaxf(red[threadIdx.x], red[threadIdx.x + st]);
        __syncthreads();
    }
    m = red[0]; __syncthreads();

    float ssum = 0.f;
    for (int j = threadIdx.x; j < NCLS; j += 256) {
        float e = expf(logits[j] - m);
        logits[j] = e; ssum += e;
    }
    red[threadIdx.x] = ssum; __syncthreads();
    for (int st = 128; st; st >>= 1) {
        if (threadIdx.x < st) red[threadIdx.x] += red[threadIdx.x + st];
        __syncthreads();
    }
    float inv = 1.0f / red[0];
    __syncthreads();

    for (int j = threadIdx.x; j < NCLS; j += 256)
        dout[(size_t)b * NCLS + j] = logits[j] * inv;
}

// ---------------------------------------------------------------------------
extern "C" void kernel_launch(void* const* d_in, const int* in_sizes, int n_in,
                              void* d_out, int out_size, void* d_ws, size_t ws_size,
                              hipStream_t stream)
{
    const float* images  = (const float*)d_in[0];
    const float* Wm      = (const float*)d_in[1];
    const float* bm      = (const float*)d_in[2];
    const float* cls_tok = (const float*)d_in[3];
    const float* pe      = (const float*)d_in[4];
    const float* g1      = (const float*)d_in[5];
    const float* beta1   = (const float*)d_in[6];
    const float* Wq      = (const float*)d_in[7];
    const float* bq      = (const float*)d_in[8];
    const float* Wk      = (const float*)d_in[9];
    const float* bk      = (const float*)d_in[10];
    const float* Wv      = (const float*)d_in[11];
    const float* bv      = (const float*)d_in[12];
    const float* g2      = (const float*)d_in[13];
    const float* beta2   = (const float*)d_in[14];
    const float* W1      = (const float*)d_in[15];
    const float* b1      = (const float*)d_in[16];
    const float* W2      = (const float*)d_in[17];
    const float* b2      = (const float*)d_in[18];
    const float* Wc      = (const float*)d_in[19];
    const float* bc      = (const float*)d_in[20];
    float* outp = (float*)d_out;

    const int M  = BATCH * SEQ;           // 3152
    const int MP = BATCH * NPATCHES;      // 3136

    char* ws = (char*)d_ws;
    float* out  = (float*)ws; ws += (size_t)MPAD * 768 * 4;
    bf16*  xb   = (bf16*) ws; ws += (size_t)MPAD * 768 * 2;
    float* qkv  = (float*)ws; ws += (size_t)MPAD * 2304 * 4;
    bf16*  h    = (bf16*) ws; ws += (size_t)MPAD * 3072 * 2;
    bf16*  wqkv = (bf16*) ws; ws += (size_t)2304 * 768 * 2;
    bf16*  w1b  = (bf16*) ws; ws += (size_t)3072 * 768 * 2;
    bf16*  w2b  = (bf16*) ws; ws += (size_t)768 * 3072 * 2;
    float* bqkv = (float*)ws; ws += 2304 * 4;
    bf16*  wmb  = (bf16*) ws; ws += (size_t)768 * 768 * 2;
    // overlays inside h (unused until first MLP1)
    bf16*  patches = (bf16*)h;                                     // MPAD x 768 bf16
    float* tokens  = (float*)((char*)h + (size_t)MPAD * 768 * 2);  // MP x 768 fp32

    // --- patch embedding ---
    f2b_kernel<<<576, 256, 0, stream>>>(Wm, wmb, 768 * 768);
    int tot_p = MP * 768;
    patchify_kernel<<<(tot_p + 255) / 256, 256, 0, stream>>>(images, patches, tot_p);
    mfma_gemm<<<dim3(768 / 128, (MP + 127) / 128), 256, 0, stream>>>(
        (const ushort_t*)patches, (const ushort_t*)wmb, bm, tokens, nullptr,
        MP, 768, 768, 0);
    int tot_a = M * 768;
    assemble_kernel<<<(tot_a + 255) / 256, 256, 0, stream>>>(tokens, cls_tok, pe, out, tot_a);

    const int MB = (M + 127) / 128;  // 25
    const int conv_blocks = (CONV_VECS + BIAS_VECS + 255) / 256;

    for (int l = 0; l < NLAYER; ++l) {
        convert_layer_kernel<<<conv_blocks, 256, 0, stream>>>(
            Wq + (size_t)l * 768 * 768, Wk + (size_t)l * 768 * 768,
            Wv + (size_t)l * 768 * 768, W1 + (size_t)l * NMLP * 768,
            W2 + (size_t)l * 768 * NMLP, bq + l * 768, bk + l * 768, bv + l * 768,
            wqkv, w1b, w2b, bqkv);

        ln_kernel<<<M, 256, 0, stream>>>(out, g1 + l * 768, beta1 + l * 768, xb);
        mfma_gemm<<<dim3(2304 / 128, MB), 256, 0, stream>>>(
            (const ushort_t*)xb, (const ushort_t*)wqkv, bqkv, qkv, nullptr,
            M, 2304, 768, 0);
        attn_kernel<<<dim3(SEQ, BATCH * NHEAD), 64, 0, stream>>>(qkv, out);
        ln_kernel<<<M, 256, 0, stream>>>(out, g2 + l * 768, beta2 + l * 768, xb);
        mfma_gemm<<<dim3(NMLP / 128, MB), 256, 0, stream>>>(
            (const ushort_t*)xb, (const ushort_t*)w1b, b1 + l * NMLP, nullptr, h,
            M, NMLP, 768, 1);
        mfma_gemm<<<dim3(768 / 128, MB), 256, 0, stream>>>(
            (const ushort_t*)h, (const ushort_t*)w2b, b2 + l * 768, out, nullptr,
            M, 768, NMLP, 2);
    }

    cls_kernel<<<BATCH, 256, 0, stream>>>(out, Wc, bc, outp);
}

// Round 4
// 2861.467 us; speedup vs baseline: 7.8570x; 2.3455x over previous
//
#include <hip/hip_runtime.h>
#include <hip/hip_bf16.h>
#include <math.h>

typedef __hip_bfloat16 bf16;
typedef unsigned short ushort_t;
typedef short bf16x8 __attribute__((ext_vector_type(8)));
typedef float f32x4 __attribute__((ext_vector_type(4)));

// Problem constants
static constexpr int BATCH = 16;
static constexpr int SEQ   = 197;   // NP*NP + 1
static constexpr int NHEAD = 12;
static constexpr int NMLP  = 3072;
static constexpr int NLAYER= 12;
static constexpr int NCLS  = 1000;
static constexpr int NPATCHES = 196;
static constexpr int MPAD  = 3200;  // padded row count for activation buffers

__device__ __forceinline__ ushort_t f2bu(float x) {
    bf16 v = __float2bfloat16(x);
    return *(ushort_t*)&v;
}

// ---------------------------------------------------------------------------
// async global->LDS, 16B per lane
// ---------------------------------------------------------------------------
__device__ __forceinline__ void load_lds16(const void* g, void* l) {
    __builtin_amdgcn_global_load_lds(
        (const __attribute__((address_space(1))) void*)g,
        (__attribute__((address_space(3))) void*)l, 16, 0, 0);
}

// ---------------------------------------------------------------------------
// MFMA GEMM: C[M,N] = op(A[M,K]bf16 @ B[N,K]^T bf16 + bias)
//   mode 0: Cf = v (fp32)
//   mode 1: Cb = bf16(gelu(v))
//   mode 2: Cf += v (fp32 residual accumulate)
// 128x128 tile, BK=32, 4 waves (2x2), 4x4 16x16x32 MFMAs per wave.
// ---------------------------------------------------------------------------
__global__ __launch_bounds__(256) void mfma_gemm(
    const ushort_t* __restrict__ A, const ushort_t* __restrict__ B,
    const float* __restrict__ bias, float* __restrict__ Cf,
    bf16* __restrict__ Cb, int M, int N, int K, int mode)
{
    __shared__ ushort_t As[128 * 32];
    __shared__ ushort_t Bs[128 * 32];

    const int t  = threadIdx.x;
    const int m0 = blockIdx.y * 128;
    const int n0 = blockIdx.x * 128;

    const int srow = t >> 2;                       // 0..63
    const int sp   = (t & 3) ^ ((srow >> 1) & 3);  // swizzled k-part to FETCH
    const int skp  = sp * 8;                       // shorts

    const int wave = t >> 6;
    const int lane = t & 63;
    const int wm   = (wave >> 1) * 64;
    const int wn   = (wave & 1) * 64;
    const int quad = lane >> 4;
    const int l16  = lane & 15;

    f32x4 acc[4][4] = {};

    const ushort_t* gA0 = A + (size_t)(m0 + srow) * K + skp;
    const ushort_t* gA1 = A + (size_t)(m0 + 64 + srow) * K + ((t & 3) ^ (((srow + 64) >> 1) & 3)) * 8;
    const ushort_t* gB0 = B + (size_t)(n0 + srow) * K + skp;
    const ushort_t* gB1 = B + (size_t)(n0 + 64 + srow) * K + ((t & 3) ^ (((srow + 64) >> 1) & 3)) * 8;
    ushort_t* lA0 = &As[t * 8];
    ushort_t* lA1 = &As[(t + 256) * 8];
    ushort_t* lB0 = &Bs[t * 8];
    ushort_t* lB1 = &Bs[(t + 256) * 8];

    for (int k0 = 0; k0 < K; k0 += 32) {
        load_lds16(gA0 + k0, lA0);
        load_lds16(gA1 + k0, lA1);
        load_lds16(gB0 + k0, lB0);
        load_lds16(gB1 + k0, lB1);
        __syncthreads();

        bf16x8 af[4], bfr[4];
        #pragma unroll
        for (int i = 0; i < 4; ++i) {
            int row = wm + i * 16 + l16;
            int s = quad ^ ((row >> 1) & 3);
            af[i] = *(const bf16x8*)&As[row * 32 + s * 8];
        }
        #pragma unroll
        for (int j = 0; j < 4; ++j) {
            int row = wn + j * 16 + l16;
            int s = quad ^ ((row >> 1) & 3);
            bfr[j] = *(const bf16x8*)&Bs[row * 32 + s * 8];
        }
        #pragma unroll
        for (int i = 0; i < 4; ++i)
            #pragma unroll
            for (int j = 0; j < 4; ++j)
                acc[i][j] = __builtin_amdgcn_mfma_f32_16x16x32_bf16(
                    af[i], bfr[j], acc[i][j], 0, 0, 0);
        __syncthreads();
    }

    #pragma unroll
    for (int i = 0; i < 4; ++i) {
        int mrow = m0 + wm + i * 16 + quad * 4;
        #pragma unroll
        for (int j = 0; j < 4; ++j) {
            int col = n0 + wn + j * 16 + l16;
            float bv = bias ? bias[col] : 0.0f;
            #pragma unroll
            for (int r = 0; r < 4; ++r) {
                int m = mrow + r;
                if (m >= M) continue;
                float v = acc[i][j][r] + bv;
                size_t idx = (size_t)m * N + col;
                if (mode == 1) {
                    v = 0.5f * v * (1.0f + erff(v * 0.70710678118654752f));
                    Cb[idx] = __float2bfloat16(v);
                } else if (mode == 2) {
                    Cf[idx] += v;
                } else {
                    Cf[idx] = v;
                }
            }
        }
    }
}

// ---------------------------------------------------------------------------
// fp32 -> bf16 elementwise
// ---------------------------------------------------------------------------
__global__ void f2b_kernel(const float* __restrict__ src, bf16* __restrict__ dst, int n)
{
    int i4 = (blockIdx.x * 256 + threadIdx.x) * 4;
    for (; i4 < n; i4 += gridDim.x * 1024) {
        float4 v = *(const float4*)(src + i4);
        dst[i4 + 0] = __float2bfloat16(v.x);
        dst[i4 + 1] = __float2bfloat16(v.y);
        dst[i4 + 2] = __float2bfloat16(v.z);
        dst[i4 + 3] = __float2bfloat16(v.w);
    }
}

// ---------------------------------------------------------------------------
// Per-layer weight conversion
// ---------------------------------------------------------------------------
static constexpr int QKV_ELEMS = 3 * 768 * 768;
static constexpr int W1_ELEMS  = 3072 * 768;
static constexpr int CONV_VECS = (QKV_ELEMS + 2 * W1_ELEMS) / 4;
static constexpr int BIAS_VECS = 2304 / 4;

__global__ void convert_layer_kernel(
    const float* __restrict__ Wq, const float* __restrict__ Wk,
    const float* __restrict__ Wv, const float* __restrict__ W1,
    const float* __restrict__ W2, const float* __restrict__ bq,
    const float* __restrict__ bk, const float* __restrict__ bv,
    bf16* __restrict__ wqkv, bf16* __restrict__ w1b, bf16* __restrict__ w2b,
    float* __restrict__ bqkv)
{
    int idx = blockIdx.x * 256 + threadIdx.x;
    if (idx < BIAS_VECS) {
        int j = idx * 4;
        #pragma unroll
        for (int i = 0; i < 4; ++i) {
            int jj = j + i;
            float v = (jj < 768) ? bq[jj] : (jj < 1536) ? bk[jj - 768] : bv[jj - 1536];
            bqkv[jj] = v;
        }
    }
    int w = idx - BIAS_VECS;
    if (w < 0 || w >= CONV_VECS) return;
    const float* src;
    bf16* dst;
    int e;
    if (w < QKV_ELEMS / 4) {
        e = w * 4;
        int tsel = e / (768 * 768);
        int off = e - tsel * 768 * 768;
        src = (tsel == 0 ? Wq : tsel == 1 ? Wk : Wv) + off;
        dst = wqkv + tsel * 768 * 768 + off;
    } else if (w < QKV_ELEMS / 4 + W1_ELEMS / 4) {
        e = (w - QKV_ELEMS / 4) * 4;
        src = W1 + e;
        dst = w1b + e;
    } else {
        e = (w - QKV_ELEMS / 4 - W1_ELEMS / 4) * 4;
        src = W2 + e;
        dst = w2b + e;
    }
    float4 v = *(const float4*)src;
    dst[0] = __float2bfloat16(v.x);
    dst[1] = __float2bfloat16(v.y);
    dst[2] = __float2bfloat16(v.z);
    dst[3] = __float2bfloat16(v.w);
}

// ---------------------------------------------------------------------------
// Patchify
// ---------------------------------------------------------------------------
__global__ void patchify_kernel(const float* __restrict__ images,
                                bf16* __restrict__ patches, int total)
{
    int idx = blockIdx.x * 256 + threadIdx.x;
    if (idx >= total) return;
    int kidx = idx % 768;
    int p = (idx / 768) % NPATCHES;
    int b = idx / (768 * NPATCHES);
    int c  = kidx >> 8;
    int rem = kidx & 255;
    int iy = rem >> 4, ix = rem & 15;
    int py = p / 14, px = p % 14;
    size_t src = (((size_t)(b * 3 + c) * 224) + py * 16 + iy) * 224 + px * 16 + ix;
    patches[idx] = __float2bfloat16(images[src]);
}

// ---------------------------------------------------------------------------
// Assemble residual stream (fp32)
// ---------------------------------------------------------------------------
__global__ void assemble_kernel(const float* __restrict__ tokens,
                                const float* __restrict__ cls,
                                const float* __restrict__ pe,
                                float* __restrict__ out, int total)
{
    int idx = blockIdx.x * 256 + threadIdx.x;
    if (idx >= total) return;
    int d = idx % 768;
    int s = (idx / 768) % SEQ;
    int b = idx / (768 * SEQ);
    float v = (s == 0) ? cls[d]
                       : tokens[((size_t)b * NPATCHES + (s - 1)) * 768 + d];
    out[idx] = v + pe[(size_t)s * 768 + d];
}

// ---------------------------------------------------------------------------
// LayerNorm (768), fp32 in -> bf16 out
// ---------------------------------------------------------------------------
__global__ __launch_bounds__(256) void ln_kernel(const float* __restrict__ inp,
                                                 const float* __restrict__ g,
                                                 const float* __restrict__ beta,
                                                 bf16* __restrict__ xout)
{
    int r = blockIdx.x;
    const float* rowp = inp + (size_t)r * 768;
    float vals[3];
    float s = 0.f, s2 = 0.f;
    #pragma unroll
    for (int i = 0; i < 3; ++i) {
        float v = rowp[threadIdx.x + 256 * i];
        vals[i] = v; s += v; s2 += v * v;
    }
    __shared__ float rs[256], rs2[256];
    rs[threadIdx.x] = s; rs2[threadIdx.x] = s2;
    __syncthreads();
    for (int st = 128; st; st >>= 1) {
        if (threadIdx.x < st) {
            rs[threadIdx.x]  += rs[threadIdx.x + st];
            rs2[threadIdx.x] += rs2[threadIdx.x + st];
        }
        __syncthreads();
    }
    float mean = rs[0] * (1.0f / 768.0f);
    float var  = rs2[0] * (1.0f / 768.0f) - mean * mean;
    float rstd = rsqrtf(var + 1e-5f);
    #pragma unroll
    for (int i = 0; i < 3; ++i) {
        int d = threadIdx.x + 256 * i;
        xout[(size_t)r * 768 + d] =
            __float2bfloat16((vals[i] - mean) * rstd * g[d] + beta[d]);
    }
}

// ---------------------------------------------------------------------------
// MFMA attention: one block per (b,h). qkv fp32 [M,2304] (q|k|v).
// K staged bf16 row-major (stride 72), V^T bf16 (stride 232), t padded to 224.
// Each wave: q-tiles of 16; QK^T -> in-reg softmax -> P via per-wave LDS
// (C-layout -> A-layout) -> PV -> scale 1/l -> += residual out.
// Dynamic LDS: Ks 16128 + Vt 14848 + Ps 4*3712 ushorts = 91648 B.
// ---------------------------------------------------------------------------
static constexpr int ATTN_LDS = (224 * 72 + 64 * 232 + 4 * 16 * 232) * 2;

__global__ __launch_bounds__(256) void attn_mfma_kernel(
    const float* __restrict__ qkv, float* __restrict__ out)
{
    extern __shared__ ushort_t smem[];
    ushort_t* Ks = smem;                  // [224][72]
    ushort_t* Vt = smem + 224 * 72;       // [64][232]
    ushort_t* Ps = Vt + 64 * 232;         // [4][16*232]

    const int bh = blockIdx.x;
    const int b = bh / NHEAD, h = bh % NHEAD;
    const int t = threadIdx.x;
    const int wave = t >> 6, lane = t & 63;
    const int quad = lane >> 4, l16 = lane & 15;

    // --- stage K and V^T (zero-pad rows t >= SEQ) ---
    for (int i = t; i < 224 * 16; i += 256) {
        int tr = i >> 4, e4 = (i & 15) << 2;
        float4 kv = {0.f, 0.f, 0.f, 0.f}, vv = {0.f, 0.f, 0.f, 0.f};
        if (tr < SEQ) {
            const float* base = qkv + (size_t)(b * SEQ + tr) * 2304 + h * 64 + e4;
            kv = *(const float4*)(base + 768);
            vv = *(const float4*)(base + 1536);
        }
        ushort_t kp[4] = {f2bu(kv.x), f2bu(kv.y), f2bu(kv.z), f2bu(kv.w)};
        *(uint2*)&Ks[tr * 72 + e4] = *(const uint2*)kp;
        Vt[(e4 + 0) * 232 + tr] = f2bu(vv.x);
        Vt[(e4 + 1) * 232 + tr] = f2bu(vv.y);
        Vt[(e4 + 2) * 232 + tr] = f2bu(vv.z);
        Vt[(e4 + 3) * 232 + tr] = f2bu(vv.w);
    }
    __syncthreads();

    bf16* pw = (bf16*)(Ps + wave * 16 * 232);

    for (int qt = wave; qt < 13; qt += 4) {
        const int q0 = qt * 16;

        // Q A-fragments (2 k-chunks of 32) straight from global
        bf16x8 qf[2];
        #pragma unroll
        for (int c = 0; c < 2; ++c) {
            const float* qp = qkv + (size_t)(b * SEQ + q0 + l16) * 2304
                            + h * 64 + c * 32 + quad * 8;
            float4 a = *(const float4*)qp;
            float4 b2 = *(const float4*)(qp + 4);
            qf[c][0] = (short)f2bu(a.x);  qf[c][1] = (short)f2bu(a.y);
            qf[c][2] = (short)f2bu(a.z);  qf[c][3] = (short)f2bu(a.w);
            qf[c][4] = (short)f2bu(b2.x); qf[c][5] = (short)f2bu(b2.y);
            qf[c][6] = (short)f2bu(b2.z); qf[c][7] = (short)f2bu(b2.w);
        }

        // S = Q K^T over 14 t-tiles
        f32x4 sc[14] = {};
        #pragma unroll
        for (int tt = 0; tt < 14; ++tt) {
            #pragma unroll
            for (int c = 0; c < 2; ++c) {
                bf16x8 kf = *(const bf16x8*)&Ks[(tt * 16 + l16) * 72 + c * 32 + quad * 8];
                sc[tt] = __builtin_amdgcn_mfma_f32_16x16x32_bf16(qf[c], kf, sc[tt], 0, 0, 0);
            }
        }

        // scale + mask, row max
        f32x4 m4;
        #pragma unroll
        for (int r = 0; r < 4; ++r) m4[r] = -3.4e38f;
        #pragma unroll
        for (int tt = 0; tt < 14; ++tt) {
            int tg = tt * 16 + l16;
            #pragma unroll
            for (int r = 0; r < 4; ++r) {
                sc[tt][r] = (tg < SEQ) ? sc[tt][r] * 0.125f : -1e30f;
                m4[r] = fmaxf(m4[r], sc[tt][r]);
            }
        }
        #pragma unroll
        for (int off = 1; off < 16; off <<= 1)
            #pragma unroll
            for (int r = 0; r < 4; ++r)
                m4[r] = fmaxf(m4[r], __shfl_xor(m4[r], off));

        // exp + row sum
        f32x4 l4 = {};
        #pragma unroll
        for (int tt = 0; tt < 14; ++tt)
            #pragma unroll
            for (int r = 0; r < 4; ++r) {
                float p = __expf(sc[tt][r] - m4[r]);
                sc[tt][r] = p;
                l4[r] += p;
            }
        #pragma unroll
        for (int off = 1; off < 16; off <<= 1)
            #pragma unroll
            for (int r = 0; r < 4; ++r)
                l4[r] += __shfl_xor(l4[r], off);

        // P (C-layout) -> per-wave LDS (A-layout source)
        #pragma unroll
        for (int tt = 0; tt < 14; ++tt)
            #pragma unroll
            for (int r = 0; r < 4; ++r)
                pw[(quad * 4 + r) * 232 + tt * 16 + l16] = __float2bfloat16(sc[tt][r]);

        // O = P V  (7 k-chunks of 32, 4 e-tiles of 16)
        f32x4 oa[4] = {};
        #pragma unroll
        for (int c = 0; c < 7; ++c) {
            bf16x8 pf = *(const bf16x8*)&((ushort_t*)pw)[l16 * 232 + c * 32 + quad * 8];
            #pragma unroll
            for (int nt = 0; nt < 4; ++nt) {
                bf16x8 vf = *(const bf16x8*)&Vt[(nt * 16 + l16) * 232 + c * 32 + quad * 8];
                oa[nt] = __builtin_amdgcn_mfma_f32_16x16x32_bf16(pf, vf, oa[nt], 0, 0, 0);
            }
        }

        // accumulate into residual
        #pragma unroll
        for (int r = 0; r < 4; ++r) {
            int q = q0 + quad * 4 + r;
            if (q >= SEQ) continue;
            float rl = 1.0f / l4[r];
            float* orow = out + (size_t)(b * SEQ + q) * 768 + h * 64;
            #pragma unroll
            for (int nt = 0; nt < 4; ++nt)
                orow[nt * 16 + l16] += oa[nt][r] * rl;
        }
    }
}

// ---------------------------------------------------------------------------
// Classifier stage 1: logits[b,j] = pooled(b) . Wc[j] + bc[j]
// grid (4, BATCH), 256 threads
// ---------------------------------------------------------------------------
__global__ __launch_bounds__(256) void cls_logits_kernel(
    const float* __restrict__ out, const float* __restrict__ Wc,
    const float* __restrict__ bc, float* __restrict__ logits)
{
    int b = blockIdx.y;
    int j = blockIdx.x * 256 + threadIdx.x;
    __shared__ float pooled[768];
    for (int d = threadIdx.x; d < 768; d += 256)
        pooled[d] = out[(size_t)b * SEQ * 768 + d];
    __syncthreads();
    if (j >= NCLS) return;
    const float* wr = Wc + (size_t)j * 768;
    float acc = 0.f;
    for (int d = 0; d < 768; ++d) acc += pooled[d] * wr[d];
    logits[b * NCLS + j] = acc + bc[j];
}

// ---------------------------------------------------------------------------
// Classifier stage 2: softmax over 1000 logits per batch row
// ---------------------------------------------------------------------------
__global__ __launch_bounds__(256) void cls_softmax_kernel(
    const float* __restrict__ logits, float* __restrict__ dout)
{
    int b = blockIdx.x;
    __shared__ float red[256];
    const float* lg = logits + b * NCLS;

    float m = -3.4e38f;
    for (int j = threadIdx.x; j < NCLS; j += 256) m = fmaxf(m, lg[j]);
    red[threadIdx.x] = m; __syncthreads();
    for (int st = 128; st; st >>= 1) {
        if (threadIdx.x < st) red[threadIdx.x] = fmaxf(red[threadIdx.x], red[threadIdx.x + st]);
        __syncthreads();
    }
    m = red[0]; __syncthreads();

    float ssum = 0.f;
    for (int j = threadIdx.x; j < NCLS; j += 256) ssum += __expf(lg[j] - m);
    red[threadIdx.x] = ssum; __syncthreads();
    for (int st = 128; st; st >>= 1) {
        if (threadIdx.x < st) red[threadIdx.x] += red[threadIdx.x + st];
        __syncthreads();
    }
    float inv = 1.0f / red[0];
    __syncthreads();

    for (int j = threadIdx.x; j < NCLS; j += 256)
        dout[(size_t)b * NCLS + j] = __expf(lg[j] - m) * inv;
}

// ---------------------------------------------------------------------------
extern "C" void kernel_launch(void* const* d_in, const int* in_sizes, int n_in,
                              void* d_out, int out_size, void* d_ws, size_t ws_size,
                              hipStream_t stream)
{
    const float* images  = (const float*)d_in[0];
    const float* Wm      = (const float*)d_in[1];
    const float* bm      = (const float*)d_in[2];
    const float* cls_tok = (const float*)d_in[3];
    const float* pe      = (const float*)d_in[4];
    const float* g1      = (const float*)d_in[5];
    const float* beta1   = (const float*)d_in[6];
    const float* Wq      = (const float*)d_in[7];
    const float* bq      = (const float*)d_in[8];
    const float* Wk      = (const float*)d_in[9];
    const float* bk      = (const float*)d_in[10];
    const float* Wv      = (const float*)d_in[11];
    const float* bv      = (const float*)d_in[12];
    const float* g2      = (const float*)d_in[13];
    const float* beta2   = (const float*)d_in[14];
    const float* W1      = (const float*)d_in[15];
    const float* b1      = (const float*)d_in[16];
    const float* W2      = (const float*)d_in[17];
    const float* b2      = (const float*)d_in[18];
    const float* Wc      = (const float*)d_in[19];
    const float* bc      = (const float*)d_in[20];
    float* outp = (float*)d_out;

    const int M  = BATCH * SEQ;           // 3152
    const int MP = BATCH * NPATCHES;      // 3136

    char* ws = (char*)d_ws;
    float* out  = (float*)ws; ws += (size_t)MPAD * 768 * 4;
    bf16*  xb   = (bf16*) ws; ws += (size_t)MPAD * 768 * 2;
    float* qkv  = (float*)ws; ws += (size_t)MPAD * 2304 * 4;
    bf16*  h    = (bf16*) ws; ws += (size_t)MPAD * 3072 * 2;
    bf16*  wqkv = (bf16*) ws; ws += (size_t)2304 * 768 * 2;
    bf16*  w1b  = (bf16*) ws; ws += (size_t)3072 * 768 * 2;
    bf16*  w2b  = (bf16*) ws; ws += (size_t)768 * 3072 * 2;
    float* bqkv = (float*)ws; ws += 2304 * 4;
    bf16*  wmb  = (bf16*) ws; ws += (size_t)768 * 768 * 2;
    float* logits = (float*)ws; ws += (size_t)BATCH * NCLS * 4;
    // overlays inside h (unused until first MLP1)
    bf16*  patches = (bf16*)h;
    float* tokens  = (float*)((char*)h + (size_t)MPAD * 768 * 2);

    hipFuncSetAttribute((const void*)attn_mfma_kernel,
                        hipFuncAttributeMaxDynamicSharedMemorySize, ATTN_LDS);

    // --- patch embedding ---
    f2b_kernel<<<576, 256, 0, stream>>>(Wm, wmb, 768 * 768);
    int tot_p = MP * 768;
    patchify_kernel<<<(tot_p + 255) / 256, 256, 0, stream>>>(images, patches, tot_p);
    mfma_gemm<<<dim3(768 / 128, (MP + 127) / 128), 256, 0, stream>>>(
        (const ushort_t*)patches, (const ushort_t*)wmb, bm, tokens, nullptr,
        MP, 768, 768, 0);
    int tot_a = M * 768;
    assemble_kernel<<<(tot_a + 255) / 256, 256, 0, stream>>>(tokens, cls_tok, pe, out, tot_a);

    const int MB = (M + 127) / 128;  // 25
    const int conv_blocks = (CONV_VECS + BIAS_VECS + 255) / 256;

    for (int l = 0; l < NLAYER; ++l) {
        convert_layer_kernel<<<conv_blocks, 256, 0, stream>>>(
            Wq + (size_t)l * 768 * 768, Wk + (size_t)l * 768 * 768,
            Wv + (size_t)l * 768 * 768, W1 + (size_t)l * NMLP * 768,
            W2 + (size_t)l * 768 * NMLP, bq + l * 768, bk + l * 768, bv + l * 768,
            wqkv, w1b, w2b, bqkv);

        ln_kernel<<<M, 256, 0, stream>>>(out, g1 + l * 768, beta1 + l * 768, xb);
        mfma_gemm<<<dim3(2304 / 128, MB), 256, 0, stream>>>(
            (const ushort_t*)xb, (const ushort_t*)wqkv, bqkv, qkv, nullptr,
            M, 2304, 768, 0);
        attn_mfma_kernel<<<BATCH * NHEAD, 256, ATTN_LDS, stream>>>(qkv, out);
        ln_kernel<<<M, 256, 0, stream>>>(out, g2 + l * 768, beta2 + l * 768, xb);
        mfma_gemm<<<dim3(NMLP / 128, MB), 256, 0, stream>>>(
            (const ushort_t*)xb, (const ushort_t*)w1b, b1 + l * NMLP, nullptr, h,
            M, NMLP, 768, 1);
        mfma_gemm<<<dim3(768 / 128, MB), 256, 0, stream>>>(
            (const ushort_t*)h, (const ushort_t*)w2b, b2 + l * 768, out, nullptr,
            M, 768, NMLP, 2);
    }

    cls_logits_kernel<<<dim3(4, BATCH), 256, 0, stream>>>(out, Wc, bc, logits);
    cls_softmax_kernel<<<BATCH, 256, 0, stream>>>(logits, outp);
}